// Round 1
// baseline (37220.737 us; speedup 1.0000x reference)
//
#include <hip/hip_runtime.h>
#include <hip/hip_cooperative_groups.h>

namespace cg = cooperative_groups;

#define SEQ    2048
#define BATCH  64
#define DIN    512
#define HID    512
#define GATES  2048      // 4*HID
#define NB     64        // blocks; block k owns 8 hidden cols -> 32 gate cols
#define NT     256       // 4 waves

typedef short bf16v8 __attribute__((ext_vector_type(8)));
typedef float f32x4  __attribute__((ext_vector_type(4)));

static __device__ __forceinline__ unsigned short f2bfbits(float f) {
    union { __bf16 h; unsigned short s; } u;
    u.h = (__bf16)f;           // RNE
    return u.s;
}

static __device__ __forceinline__ bf16v8 cvt8(const float* __restrict__ p) {
    float4 a = *(const float4*)(p);
    float4 b = *(const float4*)(p + 4);
    union { __bf16 h[8]; bf16v8 v; } u;
    u.h[0] = (__bf16)a.x; u.h[1] = (__bf16)a.y;
    u.h[2] = (__bf16)a.z; u.h[3] = (__bf16)a.w;
    u.h[4] = (__bf16)b.x; u.h[5] = (__bf16)b.y;
    u.h[6] = (__bf16)b.z; u.h[7] = (__bf16)b.w;
    return u.v;
}

static __device__ __forceinline__ float sigm(float v) {
    return 1.0f / (1.0f + __expf(-v));
}

__global__ void __launch_bounds__(NT, 1) lstm_fused(
    const float* __restrict__ x,  const float* __restrict__ c0,
    const float* __restrict__ h0, const float* __restrict__ Wi,
    const float* __restrict__ Wh, const float* __restrict__ bias,
    float* __restrict__ out, unsigned short* __restrict__ hws)
{
    // 32 cols x 512 K, bf16, col-major, XOR-swizzled 8-elem (16B) k-groups.
    // Exactly 64 KiB total.
    __shared__ unsigned short wi_lds[32 * 512];
    __shared__ unsigned short wh_lds[32 * 512];

    const int tid   = threadIdx.x;
    const int blk   = blockIdx.x;
    const int lane  = tid & 63;
    const int wv    = tid >> 6;        // wave id: batch rows [16*wv, 16*wv+16)
    const int col   = lane & 15;       // MFMA n / C-col index
    const int rgrp  = lane >> 4;       // k-group / C-row group
    const int c7    = col & 7;
    const int hbase = blk * 8;

    // ---- one-time: weight slices -> LDS (bf16) ----
    for (int idx = tid; idx < 32 * 512; idx += NT) {
        const int c = idx & 31;                         // local gate col 0..31
        const int k = idx >> 5;                         // 0..511
        const int gc = (c >> 3) * HID + hbase + (c & 7); // global col in 4H
        const int sidx = c * 512 + ((((k >> 3) ^ (c & 7)) << 3) | (k & 7));
        wi_lds[sidx] = f2bfbits(Wi[(size_t)k * GATES + gc]);
        wh_lds[sidx] = f2bfbits(Wh[(size_t)k * GATES + gc]);
    }

    // ---- one-time: init bf16 h double-buffer from h0 ----
    unsigned short* hb0 = hws;
    unsigned short* hb1 = hws + BATCH * HID;
    for (int idx = blk * NT + tid; idx < BATCH * HID; idx += NB * NT)
        hb0[idx] = f2bfbits(h0[idx]);

    cg::grid_group grid = cg::this_grid();
    __syncthreads();
    grid.sync();

    const int brow_a = wv * 16 + col;   // row this lane loads for A-frags
    const int hcol   = hbase + col;     // (only meaningful for col<8)

    // bias for this lane's two gate columns (tile0: i/f, tile1: g/o)
    const float bv0 = bias[(col >> 3) * HID + hbase + c7];
    const float bv1 = bias[((col + 16) >> 3) * HID + hbase + c7];

    // cell state lives in registers of the low-8 lanes of each 16-group
    float cv[4];
    #pragma unroll
    for (int r = 0; r < 4; ++r) {
        const int brow = wv * 16 + rgrp * 4 + r;
        cv[r] = (col < 8) ? c0[brow * HID + hcol] : 0.0f;
    }

    const size_t YS = 2 * (size_t)BATCH * HID;   // ys offset in d_out

    for (int t = 0; t < SEQ; ++t) {
        const unsigned short* hr = (t & 1) ? hb1 : hb0;
        unsigned short*       hw = (t & 1) ? hb0 : hb1;

        const float*          xrow = x + ((size_t)t * BATCH + brow_a) * DIN;
        const unsigned short* hrow = hr + brow_a * HID;

        f32x4 acc0 = {0.f, 0.f, 0.f, 0.f};   // cols 0..15  (i, f)
        f32x4 acc1 = {0.f, 0.f, 0.f, 0.f};   // cols 16..31 (g, o)

        #pragma unroll
        for (int ks = 0; ks < 16; ++ks) {
            const int kofs = ks * 32 + rgrp * 8;
            bf16v8 ah = *(const bf16v8*)(hrow + kofs);
            bf16v8 ax = cvt8(xrow + kofs);
            const int gsw = (((ks * 4 + rgrp) ^ c7) << 3);
            bf16v8 bwi0 = *(const bf16v8*)(wi_lds + col * 512 + gsw);
            bf16v8 bwh0 = *(const bf16v8*)(wh_lds + col * 512 + gsw);
            bf16v8 bwi1 = *(const bf16v8*)(wi_lds + (col + 16) * 512 + gsw);
            bf16v8 bwh1 = *(const bf16v8*)(wh_lds + (col + 16) * 512 + gsw);
            acc0 = __builtin_amdgcn_mfma_f32_16x16x32_bf16(ax, bwi0, acc0, 0, 0, 0);
            acc0 = __builtin_amdgcn_mfma_f32_16x16x32_bf16(ah, bwh0, acc0, 0, 0, 0);
            acc1 = __builtin_amdgcn_mfma_f32_16x16x32_bf16(ax, bwi1, acc1, 0, 0, 0);
            acc1 = __builtin_amdgcn_mfma_f32_16x16x32_bf16(ah, bwh1, acc1, 0, 0, 0);
        }

        // ---- gates; C/D layout: col = lane&15, row = (lane>>4)*4 + r ----
        float z0[4], z1[4], zf[4], zo[4];
        #pragma unroll
        for (int r = 0; r < 4; ++r) { z0[r] = acc0[r] + bv0; z1[r] = acc1[r] + bv1; }
        #pragma unroll
        for (int r = 0; r < 4; ++r) {
            zf[r] = __shfl_xor(z0[r], 8);   // partner col+8: f gate
            zo[r] = __shfl_xor(z1[r], 8);   // partner col+24: o gate
        }
        if (col < 8) {
            #pragma unroll
            for (int r = 0; r < 4; ++r) {
                const float ig = sigm(z0[r]);
                const float fg = sigm(zf[r]);
                const float gg = tanhf(z1[r]);
                const float og = sigm(zo[r]);
                const float cn = fg * cv[r] + ig * gg;
                cv[r] = cn;
                const float hn = og * tanhf(cn);
                const int brow = wv * 16 + rgrp * 4 + r;
                hw[brow * HID + hcol] = f2bfbits(hn);
                out[YS + ((size_t)t * BATCH + brow) * HID + hcol] = hn;
                if (t == SEQ - 1) {
                    out[(size_t)brow * HID + hcol] = cn;                      // cT
                    out[(size_t)BATCH * HID + brow * HID + hcol] = hn;        // hT
                }
            }
        }
        grid.sync();
    }
}

extern "C" void kernel_launch(void* const* d_in, const int* in_sizes, int n_in,
                              void* d_out, int out_size, void* d_ws, size_t ws_size,
                              hipStream_t stream) {
    const float* x  = (const float*)d_in[0];
    const float* c0 = (const float*)d_in[1];
    const float* h0 = (const float*)d_in[2];
    const float* Wi = (const float*)d_in[3];
    const float* Wh = (const float*)d_in[4];
    const float* b  = (const float*)d_in[5];
    float* out = (float*)d_out;
    unsigned short* hws = (unsigned short*)d_ws;  // 2 x 64x512 bf16 = 128 KiB

    void* args[] = { (void*)&x, (void*)&c0, (void*)&h0, (void*)&Wi,
                     (void*)&Wh, (void*)&b, (void*)&out, (void*)&hws };
    hipLaunchCooperativeKernel((void*)lstm_fused, dim3(NB), dim3(NT),
                               args, 0, stream);
}

// Round 3
// 30154.150 us; speedup vs baseline: 1.2343x; 1.2343x over previous
//
#include <hip/hip_runtime.h>

#define SEQ    2048
#define BATCH  64
#define DIN    512
#define HID    512
#define GATES  2048      // 4*HID
#define NB     64        // block k owns 8 hidden cols -> 32 gate cols
#define NT     256       // 4 waves
#define TC     8         // x-projection chunk length (divides SEQ)
#define ZST    33        // padded f32 row stride for zxb (bank spread)

typedef short bf16v8 __attribute__((ext_vector_type(8)));
typedef float f32x4  __attribute__((ext_vector_type(4)));

struct GBar { unsigned int cnt; unsigned int gen; };

static __device__ __forceinline__ unsigned short f2bfbits(float f) {
    union { __bf16 h; unsigned short s; } u;
    u.h = (__bf16)f;           // RNE
    return u.s;
}

static __device__ __forceinline__ bf16v8 cvt8(const float* __restrict__ p) {
    float4 a = *(const float4*)(p);
    float4 b = *(const float4*)(p + 4);
    union { __bf16 h[8]; bf16v8 v; } u;
    u.h[0] = (__bf16)a.x; u.h[1] = (__bf16)a.y;
    u.h[2] = (__bf16)a.z; u.h[3] = (__bf16)a.w;
    u.h[4] = (__bf16)b.x; u.h[5] = (__bf16)b.y;
    u.h[6] = (__bf16)b.z; u.h[7] = (__bf16)b.w;
    return u.v;
}

static __device__ __forceinline__ float sigm(float v) {
    return 1.0f / (1.0f + __expf(-v));
}
static __device__ __forceinline__ float ftanh(float v) {
    return 1.0f - 2.0f / (__expf(2.0f * v) + 1.0f);   // exact limits via __expf
}

// Lean grid barrier: NO cache flush. Cross-block data (h) moves via
// agent-scope (sc1) atomics that complete at the Infinity Cache;
// __syncthreads drains each wave's vmcnt before the arrive.
static __device__ __forceinline__ void gbar(GBar* bar, int tid, unsigned int k) {
    __syncthreads();   // s_waitcnt vmcnt(0) + s_barrier
    if (tid == 0) {
        unsigned int old = __hip_atomic_fetch_add(&bar->cnt, 1u,
                              __ATOMIC_RELAXED, __HIP_MEMORY_SCOPE_AGENT);
        if (old == k * NB - 1u) {
            __hip_atomic_store(&bar->gen, k,
                               __ATOMIC_RELAXED, __HIP_MEMORY_SCOPE_AGENT);
        } else {
            while ((int)(__hip_atomic_load(&bar->gen, __ATOMIC_RELAXED,
                                           __HIP_MEMORY_SCOPE_AGENT) - k) < 0)
                __builtin_amdgcn_s_sleep(2);
        }
    }
    __syncthreads();
}

__global__ void __launch_bounds__(NT, 1) lstm_fused(
    const float* __restrict__ x,  const float* __restrict__ c0,
    const float* __restrict__ h0, const float* __restrict__ Wi,
    const float* __restrict__ Wh, const float* __restrict__ bias,
    float* __restrict__ out, GBar* bar, unsigned short* hws)
{
    // Weights: 32 cols x 512 K each, bf16, col-major, XOR-swizzled 16B
    // k-groups (64 KiB). zxb: chunk of x@Wi results, padded stride (66 KiB).
    __shared__ unsigned short wi_lds[32 * 512];
    __shared__ unsigned short wh_lds[32 * 512];
    __shared__ float zxb[TC * 64 * ZST];

    const int tid   = threadIdx.x;
    const int blk   = blockIdx.x;
    const int lane  = tid & 63;
    const int wv    = tid >> 6;
    const int col   = lane & 15;       // MFMA n / C-col index
    const int rgrp  = lane >> 4;       // k-group / C-row group
    const int c7    = col & 7;
    const int hbase = blk * 8;

    for (int idx = tid; idx < 32 * 512; idx += NT) {
        const int c = idx & 31;
        const int k = idx >> 5;
        const int gc = (c >> 3) * HID + hbase + (c & 7);
        const int sidx = c * 512 + ((((k >> 3) ^ (c & 7)) << 3) | (k & 7));
        wi_lds[sidx] = f2bfbits(Wi[(size_t)k * GATES + gc]);
        wh_lds[sidx] = f2bfbits(Wh[(size_t)k * GATES + gc]);
    }

    // h double-buffer init: sc1 stores (cross-XCD readers next step)
    unsigned short* hb0 = hws;
    unsigned short* hb1 = hws + BATCH * HID;
    for (int idx = blk * NT + tid; idx < BATCH * HID; idx += NB * NT)
        __hip_atomic_store(&hb0[idx], f2bfbits(h0[idx]),
                           __ATOMIC_RELAXED, __HIP_MEMORY_SCOPE_AGENT);

    unsigned int barc = 1;
    gbar(bar, tid, barc++);   // weights + h0 visible

    const int brow_a = wv * 16 + col;
    const int hcol   = hbase + col;
    const float bv0 = bias[(col >> 3) * HID + hbase + c7];
    const float bv1 = bias[((col + 16) >> 3) * HID + hbase + c7];

    float cv[4];
    #pragma unroll
    for (int r = 0; r < 4; ++r) {
        const int brow = wv * 16 + rgrp * 4 + r;
        cv[r] = (col < 8) ? c0[brow * HID + hcol] : 0.0f;
    }

    const size_t YS = 2 * (size_t)BATCH * HID;

    for (int t0 = 0; t0 < SEQ; t0 += TC) {
        // ---- phase A: zxb = x_chunk @ Wi (block's 32 cols) -> LDS ----
        for (int m = wv; m < (TC * 64) >> 4; m += 4) {
            const float* xtile = x + ((size_t)t0 * 64 + m * 16 + col) * DIN;
            f32x4 a0 = {0.f, 0.f, 0.f, 0.f};
            f32x4 a1 = {0.f, 0.f, 0.f, 0.f};
            #pragma unroll
            for (int ks = 0; ks < 16; ++ks) {
                const int kofs = ks * 32 + rgrp * 8;
                bf16v8 axv = cvt8(xtile + kofs);
                const int gsw = (((ks * 4 + rgrp) ^ c7) << 3);
                bf16v8 b0 = *(const bf16v8*)(wi_lds + col * 512 + gsw);
                bf16v8 b1 = *(const bf16v8*)(wi_lds + (col + 16) * 512 + gsw);
                a0 = __builtin_amdgcn_mfma_f32_16x16x32_bf16(axv, b0, a0, 0, 0, 0);
                a1 = __builtin_amdgcn_mfma_f32_16x16x32_bf16(axv, b1, a1, 0, 0, 0);
            }
            #pragma unroll
            for (int r = 0; r < 4; ++r) {
                const int row = m * 16 + rgrp * 4 + r;
                zxb[row * ZST + col]      = a0[r];
                zxb[row * ZST + col + 16] = a1[r];
            }
        }
        __syncthreads();

        // ---- phase B: recurrence over the chunk ----
        for (int tt = 0; tt < TC; ++tt) {
            const int t = t0 + tt;
            const unsigned short* hr = (t & 1) ? hb1 : hb0;
            unsigned short*       hw = (t & 1) ? hb0 : hb1;
            const unsigned short* hrow = hr + brow_a * HID;

            f32x4 acc0, acc1;
            #pragma unroll
            for (int r = 0; r < 4; ++r) {
                const int row = tt * 64 + wv * 16 + rgrp * 4 + r;
                acc0[r] = zxb[row * ZST + col]      + bv0;
                acc1[r] = zxb[row * ZST + col + 16] + bv1;
            }

            #pragma unroll
            for (int ks = 0; ks < 16; ++ks) {
                const int kofs = ks * 32 + rgrp * 8;
                union { unsigned long long q[2]; bf16v8 v; } hu;
                hu.q[0] = __hip_atomic_load(
                    (const unsigned long long*)(hrow + kofs),
                    __ATOMIC_RELAXED, __HIP_MEMORY_SCOPE_AGENT);
                hu.q[1] = __hip_atomic_load(
                    (const unsigned long long*)(hrow + kofs + 4),
                    __ATOMIC_RELAXED, __HIP_MEMORY_SCOPE_AGENT);
                const int gsw = (((ks * 4 + rgrp) ^ c7) << 3);
                bf16v8 b0 = *(const bf16v8*)(wh_lds + col * 512 + gsw);
                bf16v8 b1 = *(const bf16v8*)(wh_lds + (col + 16) * 512 + gsw);
                acc0 = __builtin_amdgcn_mfma_f32_16x16x32_bf16(hu.v, b0, acc0, 0, 0, 0);
                acc1 = __builtin_amdgcn_mfma_f32_16x16x32_bf16(hu.v, b1, acc1, 0, 0, 0);
            }

            float zf[4], zo[4];
            #pragma unroll
            for (int r = 0; r < 4; ++r) {
                zf[r] = __shfl_xor(acc0[r], 8);   // partner col+8: f gate
                zo[r] = __shfl_xor(acc1[r], 8);   // partner col+24: o gate
            }
            if (col < 8) {
                #pragma unroll
                for (int r = 0; r < 4; ++r) {
                    const float ig = sigm(acc0[r]);
                    const float fg = sigm(zf[r]);
                    const float gg = ftanh(acc1[r]);
                    const float og = sigm(zo[r]);
                    const float cn = fg * cv[r] + ig * gg;
                    cv[r] = cn;
                    const float hn = og * ftanh(cn);
                    const int brow = wv * 16 + rgrp * 4 + r;
                    __hip_atomic_store(&hw[brow * HID + hcol], f2bfbits(hn),
                                       __ATOMIC_RELAXED, __HIP_MEMORY_SCOPE_AGENT);
                    out[YS + ((size_t)t * BATCH + brow) * HID + hcol] = hn;
                    if (t == SEQ - 1) {
                        out[(size_t)brow * HID + hcol] = cn;                 // cT
                        out[(size_t)BATCH * HID + brow * HID + hcol] = hn;   // hT
                    }
                }
            }
            gbar(bar, tid, barc++);
        }
    }
}

extern "C" void kernel_launch(void* const* d_in, const int* in_sizes, int n_in,
                              void* d_out, int out_size, void* d_ws, size_t ws_size,
                              hipStream_t stream) {
    const float* x  = (const float*)d_in[0];
    const float* c0 = (const float*)d_in[1];
    const float* h0 = (const float*)d_in[2];
    const float* Wi = (const float*)d_in[3];
    const float* Wh = (const float*)d_in[4];
    const float* b  = (const float*)d_in[5];
    float* out = (float*)d_out;

    // ws layout: [0,256) barrier | [256, 256+128KiB) bf16 h double-buffer
    char* wsb = (char*)d_ws;
    GBar* bar = (GBar*)wsb;
    unsigned short* hws = (unsigned short*)(wsb + 256);

    hipMemsetAsync(bar, 0, 256, stream);   // barrier state: known-zero each call

    lstm_fused<<<dim3(NB), dim3(NT), 0, stream>>>(
        x, c0, h0, Wi, Wh, b, out, bar, hws);
}

// Round 4
// 28142.145 us; speedup vs baseline: 1.3226x; 1.0715x over previous
//
#include <hip/hip_runtime.h>

#define SEQ    2048
#define BATCH  64
#define DIN    512
#define HID    512
#define GATES  2048      // 4*HID
#define NB     64        // block k owns 8 hidden cols -> 32 gate cols
#define NT     256       // 4 waves
#define TC     8         // x-projection chunk length (divides SEQ)
#define ZST    33        // padded f32 row stride for zxb

typedef short bf16v8 __attribute__((ext_vector_type(8)));
typedef float f32x4  __attribute__((ext_vector_type(4)));

static __device__ __forceinline__ unsigned short f2bfbits(float f) {
    union { __bf16 h; unsigned short s; } u;
    u.h = (__bf16)f;           // RNE
    return u.s;
}

static __device__ __forceinline__ bf16v8 cvt8(const float* __restrict__ p) {
    float4 a = *(const float4*)(p);
    float4 b = *(const float4*)(p + 4);
    union { __bf16 h[8]; bf16v8 v; } u;
    u.h[0] = (__bf16)a.x; u.h[1] = (__bf16)a.y;
    u.h[2] = (__bf16)a.z; u.h[3] = (__bf16)a.w;
    u.h[4] = (__bf16)b.x; u.h[5] = (__bf16)b.y;
    u.h[6] = (__bf16)b.z; u.h[7] = (__bf16)b.w;
    return u.v;
}

static __device__ __forceinline__ float sigm(float v) {
    return 1.0f / (1.0f + __expf(-v));
}
static __device__ __forceinline__ float ftanh(float v) {
    return 1.0f - 2.0f / (__expf(2.0f * v) + 1.0f);   // exact limits via __expf
}

// Distributed flag barrier: block b writes monotonic counter to its own
// 64B line (plain sc1 store, no RMW); wave 0 polls all 64 slots in
// parallel. h data ordering: h sc1 stores are drained by the
// __syncthreads (vmcnt 0) BEFORE the flag store issues.
static __device__ __forceinline__ void fbar(unsigned int* slots, int tid,
                                            int wv, int lane, int blk,
                                            unsigned int k) {
    __syncthreads();
    if (tid == 0)
        __hip_atomic_store(&slots[blk << 4], k,
                           __ATOMIC_RELAXED, __HIP_MEMORY_SCOPE_AGENT);
    if (wv == 0) {
        unsigned int v;
        do {
            v = __hip_atomic_load(&slots[lane << 4],
                                  __ATOMIC_RELAXED, __HIP_MEMORY_SCOPE_AGENT);
        } while (!__all(v >= k));
    }
    __syncthreads();
}

__global__ void __launch_bounds__(NT, 1) lstm_fused(
    const float* __restrict__ x,  const float* __restrict__ c0,
    const float* __restrict__ h0, const float* __restrict__ Wi,
    const float* __restrict__ Wh, const float* __restrict__ bias,
    float* __restrict__ out, unsigned int* slots, unsigned short* hws)
{
    // Weights: 32 cols x 512 K each, bf16, col-major, XOR-swizzled 16B
    // k-groups (64 KiB). zxb: chunk of x@Wi results, padded stride (66 KiB).
    __shared__ unsigned short wi_lds[32 * 512];
    __shared__ unsigned short wh_lds[32 * 512];
    __shared__ float zxb[TC * 64 * ZST];

    const int tid   = threadIdx.x;
    const int blk   = blockIdx.x;
    const int lane  = tid & 63;
    const int wv    = tid >> 6;
    const int col   = lane & 15;       // MFMA n / C-col index
    const int rgrp  = lane >> 4;       // k-group / C-row group
    const int c7    = col & 7;
    const int hbase = blk * 8;

    for (int idx = tid; idx < 32 * 512; idx += NT) {
        const int c = idx & 31;
        const int k = idx >> 5;
        const int gc = (c >> 3) * HID + hbase + (c & 7);
        const int sidx = c * 512 + ((((k >> 3) ^ (c & 7)) << 3) | (k & 7));
        wi_lds[sidx] = f2bfbits(Wi[(size_t)k * GATES + gc]);
        wh_lds[sidx] = f2bfbits(Wh[(size_t)k * GATES + gc]);
    }

    // h double-buffer init: sc1 stores (cross-XCD readers next step)
    unsigned short* hb0 = hws;
    unsigned short* hb1 = hws + BATCH * HID;
    for (int idx = blk * NT + tid; idx < BATCH * HID; idx += NB * NT)
        __hip_atomic_store(&hb0[idx], f2bfbits(h0[idx]),
                           __ATOMIC_RELAXED, __HIP_MEMORY_SCOPE_AGENT);

    fbar(slots, tid, wv, lane, blk, 1u);   // weights + h0 visible

    const int brow_a = wv * 16 + col;
    const int hcol   = hbase + col;
    const float bv0 = bias[(col >> 3) * HID + hbase + c7];
    const float bv1 = bias[((col + 16) >> 3) * HID + hbase + c7];

    float cv[4];
    #pragma unroll
    for (int r = 0; r < 4; ++r) {
        const int brow = wv * 16 + rgrp * 4 + r;
        cv[r] = (col < 8) ? c0[brow * HID + hcol] : 0.0f;
    }

    const size_t YS = 2 * (size_t)BATCH * HID;

    for (int t0 = 0; t0 < SEQ; t0 += TC) {
        // ---- phase A: zxb = x_chunk @ Wi (block's 32 cols) -> LDS ----
        for (int m = wv; m < (TC * 64) >> 4; m += 4) {
            const float* xtile = x + ((size_t)t0 * 64 + m * 16 + col) * DIN;
            f32x4 a0 = {0.f, 0.f, 0.f, 0.f};
            f32x4 a1 = {0.f, 0.f, 0.f, 0.f};
            #pragma unroll
            for (int ks = 0; ks < 16; ++ks) {
                const int kofs = ks * 32 + rgrp * 8;
                bf16v8 axv = cvt8(xtile + kofs);
                const int gsw = (((ks * 4 + rgrp) ^ c7) << 3);
                bf16v8 b0 = *(const bf16v8*)(wi_lds + col * 512 + gsw);
                bf16v8 b1 = *(const bf16v8*)(wi_lds + (col + 16) * 512 + gsw);
                a0 = __builtin_amdgcn_mfma_f32_16x16x32_bf16(axv, b0, a0, 0, 0, 0);
                a1 = __builtin_amdgcn_mfma_f32_16x16x32_bf16(axv, b1, a1, 0, 0, 0);
            }
            #pragma unroll
            for (int r = 0; r < 4; ++r) {
                const int row = m * 16 + rgrp * 4 + r;
                zxb[row * ZST + col]      = a0[r];
                zxb[row * ZST + col + 16] = a1[r];
            }
        }
        __syncthreads();

        // ---- phase B: recurrence over the chunk ----
        for (int tt = 0; tt < TC; ++tt) {
            const int t = t0 + tt;
            const unsigned int kk = (unsigned int)t + 2u;  // barrier counter
            const unsigned short* hr = (t & 1) ? hb1 : hb0;
            unsigned short*       hw = (t & 1) ? hb0 : hb1;
            const unsigned short* hrow = hr + brow_a * HID;

            f32x4 acc0, acc1;
            #pragma unroll
            for (int r = 0; r < 4; ++r) {
                const int row = tt * 64 + wv * 16 + rgrp * 4 + r;
                acc0[r] = zxb[row * ZST + col]      + bv0;
                acc1[r] = zxb[row * ZST + col + 16] + bv1;
            }

            #pragma unroll
            for (int ks = 0; ks < 16; ++ks) {
                const int kofs = ks * 32 + rgrp * 8;
                union { unsigned long long q[2]; bf16v8 v; } hu;
                hu.q[0] = __hip_atomic_load(
                    (const unsigned long long*)(hrow + kofs),
                    __ATOMIC_RELAXED, __HIP_MEMORY_SCOPE_AGENT);
                hu.q[1] = __hip_atomic_load(
                    (const unsigned long long*)(hrow + kofs + 4),
                    __ATOMIC_RELAXED, __HIP_MEMORY_SCOPE_AGENT);
                const int gsw = (((ks * 4 + rgrp) ^ c7) << 3);
                bf16v8 b0 = *(const bf16v8*)(wh_lds + col * 512 + gsw);
                bf16v8 b1 = *(const bf16v8*)(wh_lds + (col + 16) * 512 + gsw);
                acc0 = __builtin_amdgcn_mfma_f32_16x16x32_bf16(hu.v, b0, acc0, 0, 0, 0);
                acc1 = __builtin_amdgcn_mfma_f32_16x16x32_bf16(hu.v, b1, acc1, 0, 0, 0);
            }

            float zf[4], zo[4];
            #pragma unroll
            for (int r = 0; r < 4; ++r) {
                zf[r] = __shfl_xor(acc0[r], 8);   // partner col+8: f gate
                zo[r] = __shfl_xor(acc1[r], 8);   // partner col+24: o gate
            }

            float hn[4], cnl[4];
            if (col < 8) {
                #pragma unroll
                for (int r = 0; r < 4; ++r) {
                    const float ig = sigm(acc0[r]);
                    const float fg = sigm(zf[r]);
                    const float gg = ftanh(acc1[r]);
                    const float og = sigm(zo[r]);
                    const float cn = fg * cv[r] + ig * gg;
                    cv[r] = cn;
                    cnl[r] = cn;
                    hn[r] = og * ftanh(cn);
                    const int brow = wv * 16 + rgrp * 4 + r;
                    __hip_atomic_store(&hw[brow * HID + hcol], f2bfbits(hn[r]),
                                       __ATOMIC_RELAXED, __HIP_MEMORY_SCOPE_AGENT);
                }
            }

            // ---- arrive: drain h stores, publish flag ----
            __syncthreads();
            if (tid == 0)
                __hip_atomic_store(&slots[blk << 4], kk,
                                   __ATOMIC_RELAXED, __HIP_MEMORY_SCOPE_AGENT);

            // ---- deferred output stores (off the critical path) ----
            if (col < 8) {
                #pragma unroll
                for (int r = 0; r < 4; ++r) {
                    const int brow = wv * 16 + rgrp * 4 + r;
                    out[YS + ((size_t)t * BATCH + brow) * HID + hcol] = hn[r];
                    if (t == SEQ - 1) {
                        out[(size_t)brow * HID + hcol] = cnl[r];             // cT
                        out[(size_t)BATCH * HID + brow * HID + hcol] = hn[r]; // hT
                    }
                }
            }

            // ---- wait: all blocks published step t ----
            if (wv == 0) {
                unsigned int v;
                do {
                    v = __hip_atomic_load(&slots[lane << 4],
                                          __ATOMIC_RELAXED,
                                          __HIP_MEMORY_SCOPE_AGENT);
                } while (!__all(v >= kk));
            }
            __syncthreads();
        }
    }
}

extern "C" void kernel_launch(void* const* d_in, const int* in_sizes, int n_in,
                              void* d_out, int out_size, void* d_ws, size_t ws_size,
                              hipStream_t stream) {
    const float* x  = (const float*)d_in[0];
    const float* c0 = (const float*)d_in[1];
    const float* h0 = (const float*)d_in[2];
    const float* Wi = (const float*)d_in[3];
    const float* Wh = (const float*)d_in[4];
    const float* b  = (const float*)d_in[5];
    float* out = (float*)d_out;

    // ws layout: [0,4K) flag slots (64 x 64B) | [4K, 4K+128KiB) bf16 h dbuf
    char* wsb = (char*)d_ws;
    unsigned int* slots = (unsigned int*)wsb;
    unsigned short* hws = (unsigned short*)(wsb + 4096);

    hipMemsetAsync(slots, 0, 4096, stream);   // flags known-zero each call

    lstm_fused<<<dim3(NB), dim3(NT), 0, stream>>>(
        x, c0, h0, Wi, Wh, b, out, slots, hws);
}

// Round 5
// 24938.765 us; speedup vs baseline: 1.4925x; 1.1284x over previous
//
#include <hip/hip_runtime.h>

#define SEQ    2048
#define BATCH  64
#define DIN    512
#define HID    512
#define GATES  2048      // 4*HID
#define NB     64        // block k owns 8 hidden cols -> 32 gate cols
#define NT     256       // 4 waves
#define TC     8         // x-projection chunk length (divides SEQ)
#define ZST    33        // padded f32 row stride for zxb

typedef short bf16v8 __attribute__((ext_vector_type(8)));
typedef float f32x4  __attribute__((ext_vector_type(4)));

static __device__ __forceinline__ unsigned short f2bfbits(float f) {
    union { __bf16 h; unsigned short s; } u;
    u.h = (__bf16)f;           // RNE
    return u.s;
}

static __device__ __forceinline__ bf16v8 cvt8(const float* __restrict__ p) {
    float4 a = *(const float4*)(p);
    float4 b = *(const float4*)(p + 4);
    union { __bf16 h[8]; bf16v8 v; } u;
    u.h[0] = (__bf16)a.x; u.h[1] = (__bf16)a.y;
    u.h[2] = (__bf16)a.z; u.h[3] = (__bf16)a.w;
    u.h[4] = (__bf16)b.x; u.h[5] = (__bf16)b.y;
    u.h[6] = (__bf16)b.z; u.h[7] = (__bf16)b.w;
    return u.v;
}

static __device__ __forceinline__ float sigm(float v) {
    return 1.0f / (1.0f + __expf(-v));
}
static __device__ __forceinline__ float ftanh(float v) {
    return 1.0f - 2.0f / (__expf(2.0f * v) + 1.0f);   // exact limits via __expf
}

__global__ void __launch_bounds__(NT, 1) lstm_fused(
    const float* __restrict__ x,  const float* __restrict__ c0,
    const float* __restrict__ h0, const float* __restrict__ Wi,
    const float* __restrict__ Wh, const float* __restrict__ bias,
    float* __restrict__ out, unsigned int* slots, unsigned short* hws)
{
    // Weights: 32 cols x 512 K each, bf16, col-major, XOR-swizzled 16B
    // k-groups (64 KiB). zxb: x@Wi chunk (66 KiB). hxch: 64x8 bf16 (1 KiB).
    __shared__ unsigned short wi_lds[32 * 512];
    __shared__ unsigned short wh_lds[32 * 512];
    __shared__ float zxb[TC * 64 * ZST];
    __shared__ unsigned short hxch[64 * 8];

    const int tid   = threadIdx.x;
    const int blk   = blockIdx.x;
    const int lane  = tid & 63;
    const int wv    = tid >> 6;
    const int col   = lane & 15;       // MFMA n / C-col index
    const int rgrp  = lane >> 4;       // k-group / C-row group
    const int c7    = col & 7;
    const int hbase = blk * 8;

    for (int idx = tid; idx < 32 * 512; idx += NT) {
        const int c = idx & 31;
        const int k = idx >> 5;
        const int gc = (c >> 3) * HID + hbase + (c & 7);
        const int sidx = c * 512 + ((((k >> 3) ^ (c & 7)) << 3) | (k & 7));
        wi_lds[sidx] = f2bfbits(Wi[(size_t)k * GATES + gc]);
        wh_lds[sidx] = f2bfbits(Wh[(size_t)k * GATES + gc]);
    }

    // h buffers: [64 kblk][64 row][8 col] bf16 each. Init hb0 from h0.
    unsigned short* hb0 = hws;
    unsigned short* hb1 = hws + 64 * 64 * 8;
    for (int idx = blk * NT + tid; idx < 64 * 64 * 8; idx += NB * NT) {
        const int kb = idx >> 9, row = (idx >> 3) & 63, j = idx & 7;
        __hip_atomic_store(&hb0[idx], f2bfbits(h0[row * HID + kb * 8 + j]),
                           __ATOMIC_RELAXED, __HIP_MEMORY_SCOPE_AGENT);
    }

    // init barrier
    __syncthreads();
    if (tid == 0)
        __hip_atomic_store(&slots[blk << 4], 1u,
                           __ATOMIC_RELAXED, __HIP_MEMORY_SCOPE_AGENT);
    if (wv == 1) {
        unsigned int v;
        do {
            v = __hip_atomic_load(&slots[lane << 4],
                                  __ATOMIC_RELAXED, __HIP_MEMORY_SCOPE_AGENT);
        } while (!__all(v >= 1u));
    }
    __syncthreads();

    const int brow_a = wv * 16 + col;   // A-fragment batch row
    const int hcol   = hbase + col;
    const float bv0 = bias[(col >> 3) * HID + hbase + c7];
    const float bv1 = bias[((col + 16) >> 3) * HID + hbase + c7];

    float cv[4];
    #pragma unroll
    for (int r = 0; r < 4; ++r) {
        const int brow = wv * 16 + rgrp * 4 + r;
        cv[r] = (col < 8) ? c0[brow * HID + hcol] : 0.0f;
    }

    const size_t YS = 2 * (size_t)BATCH * HID;

    for (int t0 = 0; t0 < SEQ; t0 += TC) {
        // ---- phase A: zxb = x_chunk @ Wi + bias (block's 32 cols) ----
        for (int m = wv; m < (TC * 64) >> 4; m += 4) {
            const float* xtile = x + ((size_t)t0 * 64 + m * 16 + col) * DIN;
            f32x4 a0 = {0.f, 0.f, 0.f, 0.f};
            f32x4 a1 = {0.f, 0.f, 0.f, 0.f};
            #pragma unroll
            for (int ks = 0; ks < 16; ++ks) {
                const int kofs = ks * 32 + rgrp * 8;
                bf16v8 axv = cvt8(xtile + kofs);
                const int gsw = (((ks * 4 + rgrp) ^ c7) << 3);
                bf16v8 b0 = *(const bf16v8*)(wi_lds + col * 512 + gsw);
                bf16v8 b1 = *(const bf16v8*)(wi_lds + (col + 16) * 512 + gsw);
                a0 = __builtin_amdgcn_mfma_f32_16x16x32_bf16(axv, b0, a0, 0, 0, 0);
                a1 = __builtin_amdgcn_mfma_f32_16x16x32_bf16(axv, b1, a1, 0, 0, 0);
            }
            #pragma unroll
            for (int r = 0; r < 4; ++r) {
                const int row = m * 16 + rgrp * 4 + r;
                zxb[row * ZST + col]      = a0[r] + bv0;
                zxb[row * ZST + col + 16] = a1[r] + bv1;
            }
        }
        __syncthreads();

        // ---- phase B: recurrence over the chunk ----
        for (int tt = 0; tt < TC; ++tt) {
            const int t = t0 + tt;
            const unsigned int kk = (unsigned int)t + 2u;  // barrier counter
            const unsigned short* hr = (t & 1) ? hb1 : hb0;
            unsigned short*       hw = (t & 1) ? hb0 : hb1;

            // ---- hoisted h loads: ONE latency round, 32 u64 in flight ----
            unsigned long long hq0[16], hq1[16];
            {
                const unsigned long long* hsrc = (const unsigned long long*)hr;
                #pragma unroll
                for (int ks = 0; ks < 16; ++ks) {
                    const int kblk = ks * 4 + rgrp;
                    const unsigned long long* p =
                        hsrc + ((size_t)(kblk * 64 + brow_a) << 1);
                    hq0[ks] = __hip_atomic_load(p, __ATOMIC_RELAXED,
                                                __HIP_MEMORY_SCOPE_AGENT);
                    hq1[ks] = __hip_atomic_load(p + 1, __ATOMIC_RELAXED,
                                                __HIP_MEMORY_SCOPE_AGENT);
                }
            }

            f32x4 acc0, acc1;
            #pragma unroll
            for (int r = 0; r < 4; ++r) {
                const int row = tt * 64 + wv * 16 + rgrp * 4 + r;
                acc0[r] = zxb[row * ZST + col];
                acc1[r] = zxb[row * ZST + col + 16];
            }

            #pragma unroll
            for (int ks = 0; ks < 16; ++ks) {
                union { unsigned long long q[2]; bf16v8 v; } hu;
                hu.q[0] = hq0[ks];
                hu.q[1] = hq1[ks];
                const int gsw = (((ks * 4 + rgrp) ^ c7) << 3);
                bf16v8 b0 = *(const bf16v8*)(wh_lds + col * 512 + gsw);
                bf16v8 b1 = *(const bf16v8*)(wh_lds + (col + 16) * 512 + gsw);
                acc0 = __builtin_amdgcn_mfma_f32_16x16x32_bf16(hu.v, b0, acc0, 0, 0, 0);
                acc1 = __builtin_amdgcn_mfma_f32_16x16x32_bf16(hu.v, b1, acc1, 0, 0, 0);
            }

            float zf[4], zo[4];
            #pragma unroll
            for (int r = 0; r < 4; ++r) {
                zf[r] = __shfl_xor(acc0[r], 8);   // partner col+8: f gate
                zo[r] = __shfl_xor(acc1[r], 8);   // partner col+24: o gate
            }

            float hn[4], cnl[4];
            if (col < 8) {
                #pragma unroll
                for (int r = 0; r < 4; ++r) {
                    const float ig = sigm(acc0[r]);
                    const float fg = sigm(zf[r]);
                    const float gg = ftanh(acc1[r]);
                    const float og = sigm(zo[r]);
                    const float cn = fg * cv[r] + ig * gg;
                    cv[r] = cn;
                    cnl[r] = cn;
                    hn[r] = og * ftanh(cn);
                    const int brow = wv * 16 + rgrp * 4 + r;
                    hxch[brow * 8 + c7] = f2bfbits(hn[r]);   // LDS transpose
                }
            }
            __syncthreads();   // hxch complete

            // ---- export: wave 0 stores the 1 KiB slice + flag ----
            if (wv == 0) {
                const unsigned long long* sp =
                    (const unsigned long long*)(hxch + lane * 8);
                unsigned long long e0 = sp[0], e1 = sp[1];
                unsigned long long* dst = (unsigned long long*)
                    (hw + (((size_t)blk * 64 + lane) << 3));
                __hip_atomic_store(dst, e0, __ATOMIC_RELAXED,
                                   __HIP_MEMORY_SCOPE_AGENT);
                __hip_atomic_store(dst + 1, e1, __ATOMIC_RELAXED,
                                   __HIP_MEMORY_SCOPE_AGENT);
                asm volatile("s_waitcnt vmcnt(0)" ::: "memory");
                if (lane == 0)
                    __hip_atomic_store(&slots[blk << 4], kk,
                                       __ATOMIC_RELAXED,
                                       __HIP_MEMORY_SCOPE_AGENT);
            }

            // ---- deferred output stores (overlap the poll window) ----
            if (col < 8) {
                #pragma unroll
                for (int r = 0; r < 4; ++r) {
                    const int brow = wv * 16 + rgrp * 4 + r;
                    out[YS + ((size_t)t * BATCH + brow) * HID + hcol] = hn[r];
                    if (t == SEQ - 1) {
                        out[(size_t)brow * HID + hcol] = cnl[r];              // cT
                        out[(size_t)BATCH * HID + brow * HID + hcol] = hn[r]; // hT
                    }
                }
            }

            // ---- wait: all blocks published step t ----
            if (wv == 1) {
                unsigned int v;
                do {
                    v = __hip_atomic_load(&slots[lane << 4],
                                          __ATOMIC_RELAXED,
                                          __HIP_MEMORY_SCOPE_AGENT);
                } while (!__all(v >= kk));
            }
            __syncthreads();
        }
    }
}

extern "C" void kernel_launch(void* const* d_in, const int* in_sizes, int n_in,
                              void* d_out, int out_size, void* d_ws, size_t ws_size,
                              hipStream_t stream) {
    const float* x  = (const float*)d_in[0];
    const float* c0 = (const float*)d_in[1];
    const float* h0 = (const float*)d_in[2];
    const float* Wi = (const float*)d_in[3];
    const float* Wh = (const float*)d_in[4];
    const float* b  = (const float*)d_in[5];
    float* out = (float*)d_out;

    // ws layout: [0,4K) flag slots (64 x 64B) | [4K, 4K+128KiB) bf16 h dbuf
    char* wsb = (char*)d_ws;
    unsigned int* slots = (unsigned int*)wsb;
    unsigned short* hws = (unsigned short*)(wsb + 4096);

    hipMemsetAsync(slots, 0, 4096, stream);   // flags known-zero each call

    lstm_fused<<<dim3(NB), dim3(NT), 0, stream>>>(
        x, c0, h0, Wi, Wh, b, out, slots, hws);
}